// Round 4
// baseline (485.588 us; speedup 1.0000x reference)
//
#include <hip/hip_runtime.h>
#include <stdint.h>

#define TQs 2048
#define TKs 2048
#define DDs 512
#define NBs 8

typedef float f32x4 __attribute__((ext_vector_type(4)));
typedef short bf16x8 __attribute__((ext_vector_type(8)));
typedef short bf16x4 __attribute__((ext_vector_type(4)));
typedef _Float16 half8 __attribute__((ext_vector_type(8)));

__device__ __forceinline__ unsigned short f2bf(float x){
  unsigned u = __float_as_uint(x);
  return (unsigned short)((u + 0x7fffu + ((u>>16)&1u)) >> 16);
}
__device__ __forceinline__ float bf2f(unsigned short h){
  return __uint_as_float(((unsigned)h)<<16);
}

// global -> LDS direct DMA, 16B per lane; LDS dest = uniform base + lane*16.
__device__ __forceinline__ void gload16(const void* g, void* l){
  __builtin_amdgcn_global_load_lds(
      (const __attribute__((address_space(1))) unsigned int*)(unsigned long long)(uintptr_t)g,
      (__attribute__((address_space(3))) unsigned int*)(unsigned int)(uintptr_t)l,
      16, 0, 0);
}

// K0a: k (f32) -> kf (f16)
__global__ __launch_bounds__(256) void k0_kf(const float* __restrict__ kk, _Float16* __restrict__ kf){
  const long n8 = (long)NBs*TKs*DDs/8;
  for(long i = (long)blockIdx.x*256 + threadIdx.x; i < n8; i += (long)gridDim.x*256){
    f32x4 x0 = ((const f32x4*)kk)[2*i];
    f32x4 x1 = ((const f32x4*)kk)[2*i+1];
    half8 h;
    #pragma unroll
    for(int j=0;j<4;j++){ h[j] = (_Float16)x0[j]; h[4+j] = (_Float16)x1[j]; }
    ((half8*)kf)[i] = h;
  }
}

// K0b: v (b,t,d) f32 -> vt (b,d,t) bf16
__global__ __launch_bounds__(256) void k0_transpose_v(const float* __restrict__ v, short* __restrict__ vt){
  __shared__ float tile[64][65];
  int b = blockIdx.z;
  int t0 = blockIdx.x*64, d0 = blockIdx.y*64;
  int tid = threadIdx.x;
  int r = tid>>2, cs = (tid&3)*16;
  const float* src = v + ((long)b*TKs + t0 + r)*DDs + d0 + cs;
  #pragma unroll
  for(int i=0;i<4;i++){
    f32x4 x = ((const f32x4*)src)[i];
    tile[r][cs+4*i+0]=x[0]; tile[r][cs+4*i+1]=x[1]; tile[r][cs+4*i+2]=x[2]; tile[r][cs+4*i+3]=x[3];
  }
  __syncthreads();
  int dr = tid>>2, ts = (tid&3)*16;
  bf16x8 b0, b1;
  #pragma unroll
  for(int i=0;i<8;i++){ b0[i] = (short)f2bf(tile[ts+i][dr]); b1[i] = (short)f2bf(tile[ts+8+i][dr]); }
  short* dst = vt + ((long)b*DDs + d0 + dr)*TKs + t0 + ts;
  ((bf16x8*)dst)[0] = b0;
  ((bf16x8*)dst)[1] = b1;
}

// K0c: w (d,e) f32 -> wth/wtl (e,d) bf16 split
__global__ __launch_bounds__(256) void k0_wt(const float* __restrict__ wsrc,
                                             short* __restrict__ wth, short* __restrict__ wtl){
  __shared__ float tile[64][65];
  int d0 = blockIdx.x*64, e0 = blockIdx.y*64;
  int tid = threadIdx.x;
  int r = tid>>2, cs = (tid&3)*16;
  const float* src = wsrc + ((long)(d0 + r))*DDs + e0 + cs;
  #pragma unroll
  for(int i=0;i<4;i++){
    f32x4 x = ((const f32x4*)src)[i];
    tile[r][cs+4*i+0]=x[0]; tile[r][cs+4*i+1]=x[1]; tile[r][cs+4*i+2]=x[2]; tile[r][cs+4*i+3]=x[3];
  }
  __syncthreads();
  int er = tid>>2, ds = (tid&3)*16;
  bf16x8 h0,h1,l0,l1;
  #pragma unroll
  for(int i=0;i<8;i++){
    float x = tile[ds+i][er];
    unsigned short hh = f2bf(x);
    h0[i] = (short)hh; l0[i] = (short)f2bf(x - bf2f(hh));
  }
  #pragma unroll
  for(int i=0;i<8;i++){
    float x = tile[ds+8+i][er];
    unsigned short hh = f2bf(x);
    h1[i] = (short)hh; l1[i] = (short)f2bf(x - bf2f(hh));
  }
  short* dh = wth + ((long)(e0+er))*DDs + d0 + ds;
  short* dl = wtl + ((long)(e0+er))*DDs + d0 + ds;
  ((bf16x8*)dh)[0] = h0; ((bf16x8*)dh)[1] = h1;
  ((bf16x8*)dl)[0] = l0; ((bf16x8*)dl)[1] = l1;
}

// K1: qw = q @ W (bf16 3-term). Output: f16 hi/lo split.
__global__ __launch_bounds__(256,2) void k1_qw(const float* __restrict__ q,
                                               const short* __restrict__ wth, const short* __restrict__ wtl,
                                               _Float16* __restrict__ qwh, _Float16* __restrict__ qwl){
  __shared__ short qah[8192], qal[8192];
  __shared__ short wbh[8192], wbl[8192];
  int q0 = blockIdx.x*128, e0 = blockIdx.y*128;
  int tid = threadIdx.x, lane = tid&63, w4 = tid>>6;
  int wm = w4>>1, wn = w4&1;
  int i15 = lane&15, g4 = lane>>4;
  f32x4 acc[4][4];
  #pragma unroll
  for(int a=0;a<4;a++)
    #pragma unroll
    for(int bq=0;bq<4;bq++) acc[a][bq] = (f32x4){0.f,0.f,0.f,0.f};
  for(int k0=0;k0<DDs;k0+=64){
    __syncthreads();
    #pragma unroll
    for(int j=0;j<4;j++){
      int J = j*4 + w4;
      long so = (long)(e0 + (J>>1)*16 + i15)*DDs + k0 + ((J&1)*4 + g4)*8;
      gload16(wth + so, &wbh[J*512]);
      gload16(wtl + so, &wbl[J*512]);
    }
    #pragma unroll
    for(int j=0;j<4;j++){
      int c = j*256 + tid;
      int ci = c&15, cg = (c>>4)&3, cks = (c>>6)&1, crb = c>>7;
      const float* s = q + (long)(q0 + crb*16 + ci)*DDs + k0 + (cks*4+cg)*8;
      f32x4 x0 = ((const f32x4*)s)[0];
      f32x4 x1 = ((const f32x4*)s)[1];
      bf16x8 h, l;
      #pragma unroll
      for(int jj=0;jj<4;jj++){
        unsigned short hj = f2bf(x0[jj]);
        h[jj] = (short)hj; l[jj] = (short)f2bf(x0[jj]-bf2f(hj));
      }
      #pragma unroll
      for(int jj=0;jj<4;jj++){
        unsigned short hj = f2bf(x1[jj]);
        h[4+jj] = (short)hj; l[4+jj] = (short)f2bf(x1[jj]-bf2f(hj));
      }
      *(bf16x8*)&qah[c*8] = h;
      *(bf16x8*)&qal[c*8] = l;
    }
    __syncthreads();
    #pragma unroll
    for(int ks=0;ks<2;ks++){
      bf16x8 a_h[4], a_l[4], b_h[4], b_l[4];
      #pragma unroll
      for(int mf=0;mf<4;mf++){
        int c = ((wm*4+mf)*2+ks)*64 + lane;
        a_h[mf] = *(const bf16x8*)&qah[c*8];
        a_l[mf] = *(const bf16x8*)&qal[c*8];
      }
      #pragma unroll
      for(int nf=0;nf<4;nf++){
        int c = ((wn*4+nf)*2+ks)*64 + lane;
        b_h[nf] = *(const bf16x8*)&wbh[c*8];
        b_l[nf] = *(const bf16x8*)&wbl[c*8];
      }
      #pragma unroll
      for(int mf=0;mf<4;mf++)
      #pragma unroll
      for(int nf=0;nf<4;nf++){
        acc[mf][nf] = __builtin_amdgcn_mfma_f32_16x16x32_bf16(a_h[mf], b_h[nf], acc[mf][nf],0,0,0);
        acc[mf][nf] = __builtin_amdgcn_mfma_f32_16x16x32_bf16(a_h[mf], b_l[nf], acc[mf][nf],0,0,0);
        acc[mf][nf] = __builtin_amdgcn_mfma_f32_16x16x32_bf16(a_l[mf], b_h[nf], acc[mf][nf],0,0,0);
      }
    }
  }
  int rr = g4*4, cc = i15;
  #pragma unroll
  for(int mf=0;mf<4;mf++)
  #pragma unroll
  for(int nf=0;nf<4;nf++)
  #pragma unroll
  for(int r2=0;r2<4;r2++){
    long row = q0 + wm*64 + mf*16 + rr + r2;
    long col = e0 + wn*64 + nf*16 + cc;
    float s = acc[mf][nf][r2];
    _Float16 h = (_Float16)s;
    qwh[row*DDs + col] = h;
    qwl[row*DDs + col] = (_Float16)(s - (float)h);
  }
}

// K2a: scores = qw @ k^T, f16 2-term. 16-t K-tiles (LDS 2x16KB), 1024 blocks,
// per-lane online (m,l), end-of-chunk merge, raw masked S -> attn region.
__global__ __launch_bounds__(256,3) void k2a(const _Float16* __restrict__ qwh, const _Float16* __restrict__ qwl,
                                             const _Float16* __restrict__ kf,
                                             const int* __restrict__ mask, float* __restrict__ attn,
                                             float* __restrict__ m_ws, float* __restrict__ l_ws){
  __shared__ _Float16 kb[2][8192];   // 2 x 16KB, 16 cells of 16t x 32d
  int rb = blockIdx.x;               // 0..255
  int chunk = blockIdx.y;            // 0..3
  int tid = threadIdx.x, lane = tid&63, w = tid>>6;
  int b = rb>>5;
  long qrow0 = (long)rb*64 + w*16;
  int i15 = lane&15, g4 = lane>>4;
  half8 ah[16], al[16];
  {
    const _Float16* ph = qwh + (qrow0 + i15)*DDs + g4*8;
    const _Float16* pl = qwl + (qrow0 + i15)*DDs + g4*8;
    #pragma unroll
    for(int kc=0;kc<16;kc++){
      ah[kc] = *(const half8*)(ph + kc*32);
      al[kc] = *(const half8*)(pl + kc*32);
    }
  }
  float m_st[4], l_st[4];
  #pragma unroll
  for(int r=0;r<4;r++){ m_st[r]=-1e30f; l_st[r]=0.f; }
  const _Float16* kbase = kf + (long)b*TKs*DDs;
  // prologue: stage tile 0
  {
    int t0 = chunk*512;
    #pragma unroll
    for(int j=0;j<4;j++){
      int J = j*4 + w;
      long so = (long)(t0 + i15)*DDs + J*32 + g4*8;
      gload16(kbase + so, &kb[0][J*512]);
    }
  }
  __syncthreads();
  int cur = 0;
  for(int it=0; it<32; ++it){
    int t0 = chunk*512 + it*16;
    if(it < 31){
      int t1 = t0 + 16;
      #pragma unroll
      for(int j=0;j<4;j++){
        int J = j*4 + w;
        long so = (long)(t1 + i15)*DDs + J*32 + g4*8;
        gload16(kbase + so, &kb[cur^1][J*512]);
      }
    }
    int mv[4];
    #pragma unroll
    for(int r=0;r<4;r++)
      mv[r] = mask[(qrow0 + g4*4 + r)*TKs + t0 + i15];
    f32x4 acch = (f32x4){0.f,0.f,0.f,0.f};
    f32x4 accl = (f32x4){0.f,0.f,0.f,0.f};
    #pragma unroll
    for(int ks=0;ks<16;ks++){
      half8 bh = *(const half8*)&kb[cur][ks*512 + lane*8];
      acch = __builtin_amdgcn_mfma_f32_16x16x32_f16(ah[ks], bh, acch,0,0,0);
      accl = __builtin_amdgcn_mfma_f32_16x16x32_f16(al[ks], bh, accl,0,0,0);
    }
    #pragma unroll
    for(int r=0;r<4;r++){
      float s = acch[r] + accl[r];
      if(mv[r]) s = -3e38f;
      float mo = m_st[r];
      float mn = fmaxf(mo, s);
      l_st[r] = l_st[r]*__expf(mo-mn) + __expf(s-mn);
      m_st[r] = mn;
      attn[(qrow0 + g4*4 + r)*TKs + t0 + i15] = s;
    }
    __syncthreads();
    cur ^= 1;
  }
  // one-time 16-lane merge of (m,l)
  #pragma unroll
  for(int r=0;r<4;r++){
    #pragma unroll
    for(int d=1; d<16; d<<=1){
      float m2 = __shfl_xor(m_st[r], d, 16);
      float l2 = __shfl_xor(l_st[r], d, 16);
      float mn = fmaxf(m_st[r], m2);
      l_st[r] = l_st[r]*__expf(m_st[r]-mn) + l2*__expf(m2-mn);
      m_st[r] = mn;
    }
  }
  if(i15==0){
    #pragma unroll
    for(int r=0;r<4;r++){
      long row = qrow0 + g4*4 + r;
      m_ws[row*4 + chunk] = m_st[r];
      l_ws[row*4 + chunk] = l_st[r];
    }
  }
}

// K2b: merge stats, normalize S -> attention (in place), PV via bf16 MFMA.
// 512 threads (8 waves x 64 dv), 32 rows/block, grid 512 = 2 blocks/CU.
__global__ __launch_bounds__(512,4) void k2b(const short* __restrict__ vt, const float* __restrict__ m_ws,
                                             const float* __restrict__ l_ws, float* __restrict__ attn,
                                             float* __restrict__ outp){
  __shared__ short vf[2][16384];   // 2 x 32KB: 32 cells of 16dv x 32t
  __shared__ short at2[2][1024];   // 2 x 2KB: 2 cells of 16r x 32t
  __shared__ float ms[32], rls[32];
  int rb = blockIdx.x;             // 0..511
  long row0 = (long)rb*32;
  int b = rb>>6;
  int tid=threadIdx.x, lane=tid&63, w=tid>>6;
  int i15 = lane&15, g4 = lane>>4;
  const short* vb = vt + (long)b*DDs*TKs;
  float* arow = attn + row0*TKs;
  // prologue: DMA v tile 0; stats
  #pragma unroll
  for(int j=0;j<4;j++){
    int J = j*8 + w;
    long so = (long)(J*16 + i15)*TKs + g4*8;
    gload16(vb + so, &vf[0][J*512]);
  }
  if(tid < 32){
    long row = row0 + tid;
    float m0=m_ws[row*4+0], m1=m_ws[row*4+1], m2=m_ws[row*4+2], m3=m_ws[row*4+3];
    float M = fmaxf(fmaxf(m0,m1),fmaxf(m2,m3));
    float L = l_ws[row*4+0]*__expf(m0-M) + l_ws[row*4+1]*__expf(m1-M)
            + l_ws[row*4+2]*__expf(m2-M) + l_ws[row*4+3]*__expf(m3-M);
    ms[tid] = M;
    rls[tid] = 1.0f/L;
  }
  __syncthreads();
  // normalize tile 0 -> at2[0] (tids < 128: row=tid>>2, tg=tid&3)
  if(tid < 128){
    int r_ = tid>>2, tg = tid&3;
    float* p = arow + (long)r_*TKs + tg*8;
    f32x4 s0v = ((const f32x4*)p)[0];
    f32x4 s1v = ((const f32x4*)p)[1];
    float M = ms[r_], RL = rls[r_];
    f32x4 a0, a1;
    #pragma unroll
    for(int j=0;j<4;j++){ a0[j] = __expf(s0v[j]-M)*RL; a1[j] = __expf(s1v[j]-M)*RL; }
    ((f32x4*)p)[0] = a0;
    ((f32x4*)p)[1] = a1;
    bf16x8 ab;
    #pragma unroll
    for(int j=0;j<4;j++){ ab[j] = (short)f2bf(a0[j]); ab[4+j] = (short)f2bf(a1[j]); }
    int cell = r_>>4, lfr = (r_&15) | (tg<<4);
    *(bf16x8*)&at2[0][(cell*64 + lfr)*8] = ab;
  }
  __syncthreads();
  f32x4 acc[2][4];
  #pragma unroll
  for(int mf=0;mf<2;mf++)
    #pragma unroll
    for(int nf=0;nf<4;nf++) acc[mf][nf]=(f32x4){0.f,0.f,0.f,0.f};
  int c = 0;
  for(int it=0; it<64; ++it){
    f32x4 s0v, s1v;
    int r_ = tid>>2, tg = tid&3;
    if(it < 63){
      int t1 = (it+1)*32;
      #pragma unroll
      for(int j=0;j<4;j++){
        int J = j*8 + w;
        long so = (long)(J*16 + i15)*TKs + t1 + g4*8;
        gload16(vb + so, &vf[c^1][J*512]);
      }
      if(tid < 128){
        const float* p = arow + (long)r_*TKs + t1 + tg*8;
        s0v = ((const f32x4*)p)[0];
        s1v = ((const f32x4*)p)[1];
      }
    }
    // MFMA on current tile
    bf16x8 af[2], bfr[4];
    #pragma unroll
    for(int mf=0;mf<2;mf++) af[mf] = *(const bf16x8*)&at2[c][(mf*64 + lane)*8];
    #pragma unroll
    for(int nf=0;nf<4;nf++) bfr[nf] = *(const bf16x8*)&vf[c][((w*4+nf)*64 + lane)*8];
    #pragma unroll
    for(int mf=0;mf<2;mf++)
    #pragma unroll
    for(int nf=0;nf<4;nf++)
      acc[mf][nf] = __builtin_amdgcn_mfma_f32_16x16x32_bf16(af[mf], bfr[nf], acc[mf][nf],0,0,0);
    // normalize next tile into at2[c^1]
    if(it < 63 && tid < 128){
      int t1 = (it+1)*32;
      float* p = arow + (long)r_*TKs + t1 + tg*8;
      float M = ms[r_], RL = rls[r_];
      f32x4 a0, a1;
      #pragma unroll
      for(int j=0;j<4;j++){ a0[j] = __expf(s0v[j]-M)*RL; a1[j] = __expf(s1v[j]-M)*RL; }
      ((f32x4*)p)[0] = a0;
      ((f32x4*)p)[1] = a1;
      bf16x8 ab;
      #pragma unroll
      for(int j=0;j<4;j++){ ab[j] = (short)f2bf(a0[j]); ab[4+j] = (short)f2bf(a1[j]); }
      int cell = r_>>4, lfr = (r_&15) | (tg<<4);
      *(bf16x8*)&at2[c^1][(cell*64 + lfr)*8] = ab;
    }
    __syncthreads();
    c ^= 1;
  }
  #pragma unroll
  for(int mf=0;mf<2;mf++)
  #pragma unroll
  for(int nf=0;nf<4;nf++)
  #pragma unroll
  for(int r2=0;r2<4;r2++){
    long row = row0 + mf*16 + g4*4 + r2;
    long col = w*64 + nf*16 + i15;
    outp[row*DDs + col] = acc[mf][nf][r2];
  }
}

extern "C" void kernel_launch(void* const* d_in, const int* in_sizes, int n_in,
                              void* d_out, int out_size, void* d_ws, size_t ws_size,
                              hipStream_t stream) {
  const float* q    = (const float*)d_in[0];
  const float* k    = (const float*)d_in[1];
  const float* v    = (const float*)d_in[2];
  const int*   mask = (const int*)d_in[3];
  const float* wsrc = (const float*)d_in[4];
  float* outp = (float*)d_out;
  float* attn = (float*)d_out + (long)NBs*TQs*DDs;
  char* ws = (char*)d_ws;
  const long NE = (long)NBs*TKs*DDs;      // 8,388,608 elements
  _Float16* kf  = (_Float16*)ws;                 // 2NE bytes
  short*    vt  = (short*)(ws + 2*NE);           // 2NE bytes
  _Float16* qwh = (_Float16*)(ws + 4*NE);        // 2NE bytes
  _Float16* qwl = (_Float16*)(ws + 6*NE);        // 2NE bytes
  float* m_ws = (float*)(ws + 8*NE);             // 65536 f32
  float* l_ws = (float*)(ws + 8*NE + 65536*4);
  // wt split lives at the head of the attn region (dead before k2a overwrites it)
  short* wth = (short*)attn;
  short* wtl = (short*)attn + 262144;
  hipLaunchKernelGGL(k0_kf,          dim3(1024),    dim3(256), 0, stream, k, kf);
  hipLaunchKernelGGL(k0_transpose_v, dim3(32,8,8),  dim3(256), 0, stream, v, vt);
  hipLaunchKernelGGL(k0_wt,          dim3(8,8),     dim3(256), 0, stream, wsrc, wth, wtl);
  hipLaunchKernelGGL(k1_qw,          dim3(128,4),   dim3(256), 0, stream, q, wth, wtl, qwh, qwl);
  hipLaunchKernelGGL(k2a,            dim3(256,4),   dim3(256), 0, stream, qwh, qwl, kf, mask, attn, m_ws, l_ws);
  hipLaunchKernelGGL(k2b,            dim3(512),     dim3(512), 0, stream, vt, m_ws, l_ws, attn, outp);
}

// Round 5
// 354.292 us; speedup vs baseline: 1.3706x; 1.3706x over previous
//
#include <hip/hip_runtime.h>
#include <stdint.h>

#define TQs 2048
#define TKs 2048
#define DDs 512
#define NBs 8

typedef float f32x4 __attribute__((ext_vector_type(4)));
typedef float f32x2 __attribute__((ext_vector_type(2)));
typedef short bf16x8 __attribute__((ext_vector_type(8)));
typedef short bf16x4 __attribute__((ext_vector_type(4)));
typedef short bf16x2 __attribute__((ext_vector_type(2)));
typedef _Float16 half8 __attribute__((ext_vector_type(8)));

__device__ __forceinline__ unsigned short f2bf(float x){
  unsigned u = __float_as_uint(x);
  return (unsigned short)((u + 0x7fffu + ((u>>16)&1u)) >> 16);
}
__device__ __forceinline__ float bf2f(unsigned short h){
  return __uint_as_float(((unsigned)h)<<16);
}

// global -> LDS direct DMA, 16B per lane; LDS dest = uniform base + lane*16.
__device__ __forceinline__ void gload16(const void* g, void* l){
  __builtin_amdgcn_global_load_lds(
      (const __attribute__((address_space(1))) unsigned int*)(unsigned long long)(uintptr_t)g,
      (__attribute__((address_space(3))) unsigned int*)(unsigned int)(uintptr_t)l,
      16, 0, 0);
}

// K0a: k (f32) -> kf (f16)
__global__ __launch_bounds__(256) void k0_kf(const float* __restrict__ kk, _Float16* __restrict__ kf){
  const long n8 = (long)NBs*TKs*DDs/8;
  for(long i = (long)blockIdx.x*256 + threadIdx.x; i < n8; i += (long)gridDim.x*256){
    f32x4 x0 = ((const f32x4*)kk)[2*i];
    f32x4 x1 = ((const f32x4*)kk)[2*i+1];
    half8 h;
    #pragma unroll
    for(int j=0;j<4;j++){ h[j] = (_Float16)x0[j]; h[4+j] = (_Float16)x1[j]; }
    ((half8*)kf)[i] = h;
  }
}

// K0b: v (b,t,d) f32 -> vt (b,d,t) bf16
__global__ __launch_bounds__(256) void k0_transpose_v(const float* __restrict__ v, short* __restrict__ vt){
  __shared__ float tile[64][65];
  int b = blockIdx.z;
  int t0 = blockIdx.x*64, d0 = blockIdx.y*64;
  int tid = threadIdx.x;
  int r = tid>>2, cs = (tid&3)*16;
  const float* src = v + ((long)b*TKs + t0 + r)*DDs + d0 + cs;
  #pragma unroll
  for(int i=0;i<4;i++){
    f32x4 x = ((const f32x4*)src)[i];
    tile[r][cs+4*i+0]=x[0]; tile[r][cs+4*i+1]=x[1]; tile[r][cs+4*i+2]=x[2]; tile[r][cs+4*i+3]=x[3];
  }
  __syncthreads();
  int dr = tid>>2, ts = (tid&3)*16;
  bf16x8 b0, b1;
  #pragma unroll
  for(int i=0;i<8;i++){ b0[i] = (short)f2bf(tile[ts+i][dr]); b1[i] = (short)f2bf(tile[ts+8+i][dr]); }
  short* dst = vt + ((long)b*DDs + d0 + dr)*TKs + t0 + ts;
  ((bf16x8*)dst)[0] = b0;
  ((bf16x8*)dst)[1] = b1;
}

// K0c: w (d,e) f32 -> wth/wtl (e,d) bf16 split
__global__ __launch_bounds__(256) void k0_wt(const float* __restrict__ wsrc,
                                             short* __restrict__ wth, short* __restrict__ wtl){
  __shared__ float tile[64][65];
  int d0 = blockIdx.x*64, e0 = blockIdx.y*64;
  int tid = threadIdx.x;
  int r = tid>>2, cs = (tid&3)*16;
  const float* src = wsrc + ((long)(d0 + r))*DDs + e0 + cs;
  #pragma unroll
  for(int i=0;i<4;i++){
    f32x4 x = ((const f32x4*)src)[i];
    tile[r][cs+4*i+0]=x[0]; tile[r][cs+4*i+1]=x[1]; tile[r][cs+4*i+2]=x[2]; tile[r][cs+4*i+3]=x[3];
  }
  __syncthreads();
  int er = tid>>2, ds = (tid&3)*16;
  bf16x8 h0,h1,l0,l1;
  #pragma unroll
  for(int i=0;i<8;i++){
    float x = tile[ds+i][er];
    unsigned short hh = f2bf(x);
    h0[i] = (short)hh; l0[i] = (short)f2bf(x - bf2f(hh));
  }
  #pragma unroll
  for(int i=0;i<8;i++){
    float x = tile[ds+8+i][er];
    unsigned short hh = f2bf(x);
    h1[i] = (short)hh; l1[i] = (short)f2bf(x - bf2f(hh));
  }
  short* dh = wth + ((long)(e0+er))*DDs + d0 + ds;
  short* dl = wtl + ((long)(e0+er))*DDs + d0 + ds;
  ((bf16x8*)dh)[0] = h0; ((bf16x8*)dh)[1] = h1;
  ((bf16x8*)dl)[0] = l0; ((bf16x8*)dl)[1] = l1;
}

// K1: qw = q @ W (bf16 3-term). Output: f16 hi/lo split.
__global__ __launch_bounds__(256,2) void k1_qw(const float* __restrict__ q,
                                               const short* __restrict__ wth, const short* __restrict__ wtl,
                                               _Float16* __restrict__ qwh, _Float16* __restrict__ qwl){
  __shared__ short qah[8192], qal[8192];
  __shared__ short wbh[8192], wbl[8192];
  int q0 = blockIdx.x*128, e0 = blockIdx.y*128;
  int tid = threadIdx.x, lane = tid&63, w4 = tid>>6;
  int wm = w4>>1, wn = w4&1;
  int i15 = lane&15, g4 = lane>>4;
  f32x4 acc[4][4];
  #pragma unroll
  for(int a=0;a<4;a++)
    #pragma unroll
    for(int bq=0;bq<4;bq++) acc[a][bq] = (f32x4){0.f,0.f,0.f,0.f};
  for(int k0=0;k0<DDs;k0+=64){
    __syncthreads();
    #pragma unroll
    for(int j=0;j<4;j++){
      int J = j*4 + w4;
      long so = (long)(e0 + (J>>1)*16 + i15)*DDs + k0 + ((J&1)*4 + g4)*8;
      gload16(wth + so, &wbh[J*512]);
      gload16(wtl + so, &wbl[J*512]);
    }
    #pragma unroll
    for(int j=0;j<4;j++){
      int c = j*256 + tid;
      int ci = c&15, cg = (c>>4)&3, cks = (c>>6)&1, crb = c>>7;
      const float* s = q + (long)(q0 + crb*16 + ci)*DDs + k0 + (cks*4+cg)*8;
      f32x4 x0 = ((const f32x4*)s)[0];
      f32x4 x1 = ((const f32x4*)s)[1];
      bf16x8 h, l;
      #pragma unroll
      for(int jj=0;jj<4;jj++){
        unsigned short hj = f2bf(x0[jj]);
        h[jj] = (short)hj; l[jj] = (short)f2bf(x0[jj]-bf2f(hj));
      }
      #pragma unroll
      for(int jj=0;jj<4;jj++){
        unsigned short hj = f2bf(x1[jj]);
        h[4+jj] = (short)hj; l[4+jj] = (short)f2bf(x1[jj]-bf2f(hj));
      }
      *(bf16x8*)&qah[c*8] = h;
      *(bf16x8*)&qal[c*8] = l;
    }
    __syncthreads();
    #pragma unroll
    for(int ks=0;ks<2;ks++){
      bf16x8 a_h[4], a_l[4], b_h[4], b_l[4];
      #pragma unroll
      for(int mf=0;mf<4;mf++){
        int c = ((wm*4+mf)*2+ks)*64 + lane;
        a_h[mf] = *(const bf16x8*)&qah[c*8];
        a_l[mf] = *(const bf16x8*)&qal[c*8];
      }
      #pragma unroll
      for(int nf=0;nf<4;nf++){
        int c = ((wn*4+nf)*2+ks)*64 + lane;
        b_h[nf] = *(const bf16x8*)&wbh[c*8];
        b_l[nf] = *(const bf16x8*)&wbl[c*8];
      }
      #pragma unroll
      for(int mf=0;mf<4;mf++)
      #pragma unroll
      for(int nf=0;nf<4;nf++){
        acc[mf][nf] = __builtin_amdgcn_mfma_f32_16x16x32_bf16(a_h[mf], b_h[nf], acc[mf][nf],0,0,0);
        acc[mf][nf] = __builtin_amdgcn_mfma_f32_16x16x32_bf16(a_h[mf], b_l[nf], acc[mf][nf],0,0,0);
        acc[mf][nf] = __builtin_amdgcn_mfma_f32_16x16x32_bf16(a_l[mf], b_h[nf], acc[mf][nf],0,0,0);
      }
    }
  }
  int rr = g4*4, cc = i15;
  #pragma unroll
  for(int mf=0;mf<4;mf++)
  #pragma unroll
  for(int nf=0;nf<4;nf++)
  #pragma unroll
  for(int r2=0;r2<4;r2++){
    long row = q0 + wm*64 + mf*16 + rr + r2;
    long col = e0 + wn*64 + nf*16 + cc;
    float s = acc[mf][nf][r2];
    _Float16 h = (_Float16)s;
    qwh[row*DDs + col] = h;
    qwl[row*DDs + col] = (_Float16)(s - (float)h);
  }
}

// K2a: scores = qw @ k^T, f16 2-term (A split in regs, B single f16 in LDS).
// 32-t K-tiles double-buffered (2x32KB), 64 rows/block, 2 t-chunks of 1024.
__global__ __launch_bounds__(256,2) void k2a(const _Float16* __restrict__ qwh, const _Float16* __restrict__ qwl,
                                             const _Float16* __restrict__ kf,
                                             const int* __restrict__ mask, float* __restrict__ attn,
                                             float* __restrict__ m_ws, float* __restrict__ l_ws){
  __shared__ _Float16 kb[2][16384];   // 2 x 32KB
  int rb = blockIdx.x;                // 0..255
  int chunk = blockIdx.y;             // 0..1
  int tid = threadIdx.x, lane = tid&63, w = tid>>6;
  int b = rb>>5;
  long qrow0 = (long)rb*64 + w*16;
  int i15 = lane&15, g4 = lane>>4;
  half8 ah[16], al[16];
  {
    const _Float16* ph = qwh + (qrow0 + i15)*DDs + g4*8;
    const _Float16* pl = qwl + (qrow0 + i15)*DDs + g4*8;
    #pragma unroll
    for(int kc=0;kc<16;kc++){
      ah[kc] = *(const half8*)(ph + kc*32);
      al[kc] = *(const half8*)(pl + kc*32);
    }
  }
  float m_st[4], l_st[4];
  #pragma unroll
  for(int r=0;r<4;r++){ m_st[r]=-1e30f; l_st[r]=0.f; }
  const _Float16* kbase = kf + (long)b*TKs*DDs;
  // prologue: stage tile 0
  {
    int t0 = chunk*1024;
    #pragma unroll
    for(int j=0;j<8;j++){
      int J = j*4 + w;
      long so = (long)(t0 + ((J>>4)<<4) + i15)*DDs + (J&15)*32 + g4*8;
      gload16(kbase + so, &kb[0][J*512]);
    }
  }
  __syncthreads();
  int cur = 0;
  for(int it=0; it<32; ++it){
    int t0 = chunk*1024 + it*32;
    if(it < 31){
      int t1 = t0 + 32;
      #pragma unroll
      for(int j=0;j<8;j++){
        int J = j*4 + w;
        long so = (long)(t1 + ((J>>4)<<4) + i15)*DDs + (J&15)*32 + g4*8;
        gload16(kbase + so, &kb[cur^1][J*512]);
      }
    }
    int mv[2][4];
    #pragma unroll
    for(int nf=0;nf<2;nf++)
      #pragma unroll
      for(int r=0;r<4;r++)
        mv[nf][r] = mask[(qrow0 + g4*4 + r)*TKs + t0 + nf*16 + i15];
    f32x4 acc[2];
    acc[0]=(f32x4){0.f,0.f,0.f,0.f}; acc[1]=(f32x4){0.f,0.f,0.f,0.f};
    #pragma unroll
    for(int ks=0;ks<16;ks++){
      #pragma unroll
      for(int nf=0;nf<2;nf++){
        half8 bh = *(const half8*)&kb[cur][((nf*16+ks)*64 + lane)*8];
        acc[nf] = __builtin_amdgcn_mfma_f32_16x16x32_f16(ah[ks], bh, acc[nf],0,0,0);
        acc[nf] = __builtin_amdgcn_mfma_f32_16x16x32_f16(al[ks], bh, acc[nf],0,0,0);
      }
    }
    #pragma unroll
    for(int r=0;r<4;r++){
      float s0 = acc[0][r];
      float s1 = acc[1][r];
      if(mv[0][r]) s0 = -3e38f;
      if(mv[1][r]) s1 = -3e38f;
      float mo = m_st[r];
      float mn = fmaxf(mo, fmaxf(s0,s1));
      l_st[r] = l_st[r]*__expf(mo-mn) + __expf(s0-mn) + __expf(s1-mn);
      m_st[r] = mn;
      long row = qrow0 + g4*4 + r;
      attn[row*TKs + t0 + i15] = s0;
      attn[row*TKs + t0 + 16 + i15] = s1;
    }
    __syncthreads();
    cur ^= 1;
  }
  // one-time 16-lane merge of (m,l)
  #pragma unroll
  for(int r=0;r<4;r++){
    #pragma unroll
    for(int d=1; d<16; d<<=1){
      float m2 = __shfl_xor(m_st[r], d, 16);
      float l2 = __shfl_xor(l_st[r], d, 16);
      float mn = fmaxf(m_st[r], m2);
      l_st[r] = l_st[r]*__expf(m_st[r]-mn) + l2*__expf(m2-mn);
      m_st[r] = mn;
    }
  }
  if(i15==0){
    #pragma unroll
    for(int r=0;r<4;r++){
      long row = qrow0 + g4*4 + r;
      m_ws[row*2 + chunk] = m_st[r];
      l_ws[row*2 + chunk] = l_st[r];
    }
  }
}

// K2b: merge stats, normalize S -> attention (in place), PV via bf16 MFMA.
// 512 threads (8 waves x 64 dv), 32 rows/block; normalize spread over ALL threads.
__global__ __launch_bounds__(512,4) void k2b(const short* __restrict__ vt, const float* __restrict__ m_ws,
                                             const float* __restrict__ l_ws, float* __restrict__ attn,
                                             float* __restrict__ outp){
  __shared__ short vf[2][16384];   // 2 x 32KB: 32 cells of 16dv x 32t
  __shared__ short at2[2][1024];   // 2 x 2KB
  __shared__ float ms[32], rls[32];
  int rb = blockIdx.x;             // 0..511
  long row0 = (long)rb*32;
  int b = rb>>6;
  int tid=threadIdx.x, lane=tid&63, w=tid>>6;
  int i15 = lane&15, g4 = lane>>4;
  const short* vb = vt + (long)b*DDs*TKs;
  float* arow = attn + row0*TKs;
  // normalize work split: thread -> (row nr, even t-offset nt) within 32x32 tile
  int nr = tid>>4, nt = (tid&15)*2;
  int nmf = nr>>4, nrow = nr&15, ntg = nt>>3, nj = nt&7;
  int ncell = (nmf*64 + ntg*16 + nrow)*8 + nj;
  // prologue: DMA v tile 0; stats
  #pragma unroll
  for(int j=0;j<4;j++){
    int J = j*8 + w;
    long so = (long)(J*16 + i15)*TKs + g4*8;
    gload16(vb + so, &vf[0][J*512]);
  }
  if(tid < 32){
    long row = row0 + tid;
    float m0=m_ws[row*2+0], m1=m_ws[row*2+1];
    float M = fmaxf(m0,m1);
    float L = l_ws[row*2+0]*__expf(m0-M) + l_ws[row*2+1]*__expf(m1-M);
    ms[tid] = M;
    rls[tid] = 1.0f/L;
  }
  __syncthreads();
  // normalize tile 0 -> at2[0]
  {
    float* p = arow + (long)nr*TKs + nt;
    f32x2 s = *(const f32x2*)p;
    float M = ms[nr], RL = rls[nr];
    float a0 = __expf(s[0]-M)*RL, a1 = __expf(s[1]-M)*RL;
    f32x2 av; av[0]=a0; av[1]=a1;
    *(f32x2*)p = av;
    bf16x2 ab; ab[0]=(short)f2bf(a0); ab[1]=(short)f2bf(a1);
    *(bf16x2*)&at2[0][ncell] = ab;
  }
  __syncthreads();
  f32x4 acc[2][4];
  #pragma unroll
  for(int mf=0;mf<2;mf++)
    #pragma unroll
    for(int nf=0;nf<4;nf++) acc[mf][nf]=(f32x4){0.f,0.f,0.f,0.f};
  int c = 0;
  for(int it=0; it<64; ++it){
    float sx, sy;
    if(it < 63){
      int t1 = (it+1)*32;
      #pragma unroll
      for(int j=0;j<4;j++){
        int J = j*8 + w;
        long so = (long)(J*16 + i15)*TKs + t1 + g4*8;
        gload16(vb + so, &vf[c^1][J*512]);
      }
      const float* p = arow + (long)nr*TKs + t1 + nt;
      f32x2 s = *(const f32x2*)p;
      sx = s[0]; sy = s[1];
    }
    // MFMA on current tile
    bf16x8 af[2], bfr[4];
    #pragma unroll
    for(int mf=0;mf<2;mf++) af[mf] = *(const bf16x8*)&at2[c][(mf*64 + lane)*8];
    #pragma unroll
    for(int nf=0;nf<4;nf++) bfr[nf] = *(const bf16x8*)&vf[c][((w*4+nf)*64 + lane)*8];
    #pragma unroll
    for(int mf=0;mf<2;mf++)
    #pragma unroll
    for(int nf=0;nf<4;nf++)
      acc[mf][nf] = __builtin_amdgcn_mfma_f32_16x16x32_bf16(af[mf], bfr[nf], acc[mf][nf],0,0,0);
    // normalize next tile into at2[c^1]
    if(it < 63){
      int t1 = (it+1)*32;
      float* p = arow + (long)nr*TKs + t1 + nt;
      float M = ms[nr], RL = rls[nr];
      float a0 = __expf(sx-M)*RL, a1 = __expf(sy-M)*RL;
      f32x2 av; av[0]=a0; av[1]=a1;
      *(f32x2*)p = av;
      bf16x2 ab; ab[0]=(short)f2bf(a0); ab[1]=(short)f2bf(a1);
      *(bf16x2*)&at2[c^1][ncell] = ab;
    }
    __syncthreads();
    c ^= 1;
  }
  #pragma unroll
  for(int mf=0;mf<2;mf++)
  #pragma unroll
  for(int nf=0;nf<4;nf++)
  #pragma unroll
  for(int r2=0;r2<4;r2++){
    long row = row0 + mf*16 + g4*4 + r2;
    long col = w*64 + nf*16 + i15;
    outp[row*DDs + col] = acc[mf][nf][r2];
  }
}

extern "C" void kernel_launch(void* const* d_in, const int* in_sizes, int n_in,
                              void* d_out, int out_size, void* d_ws, size_t ws_size,
                              hipStream_t stream) {
  const float* q    = (const float*)d_in[0];
  const float* k    = (const float*)d_in[1];
  const float* v    = (const float*)d_in[2];
  const int*   mask = (const int*)d_in[3];
  const float* wsrc = (const float*)d_in[4];
  float* outp = (float*)d_out;
  float* attn = (float*)d_out + (long)NBs*TQs*DDs;
  char* ws = (char*)d_ws;
  const long NE = (long)NBs*TKs*DDs;      // 8,388,608 elements
  _Float16* kf  = (_Float16*)ws;                 // 2NE bytes
  short*    vt  = (short*)(ws + 2*NE);           // 2NE bytes
  _Float16* qwh = (_Float16*)(ws + 4*NE);        // 2NE bytes
  _Float16* qwl = (_Float16*)(ws + 6*NE);        // 2NE bytes
  float* m_ws = (float*)(ws + 8*NE);             // 32768 f32 used
  float* l_ws = (float*)(ws + 8*NE + 65536*4);
  // wt split lives at the head of the attn region (dead before k2a overwrites it)
  short* wth = (short*)attn;
  short* wtl = (short*)attn + 262144;
  hipLaunchKernelGGL(k0_kf,          dim3(1024),    dim3(256), 0, stream, k, kf);
  hipLaunchKernelGGL(k0_transpose_v, dim3(32,8,8),  dim3(256), 0, stream, v, vt);
  hipLaunchKernelGGL(k0_wt,          dim3(8,8),     dim3(256), 0, stream, wsrc, wth, wtl);
  hipLaunchKernelGGL(k1_qw,          dim3(128,4),   dim3(256), 0, stream, q, wth, wtl, qwh, qwl);
  hipLaunchKernelGGL(k2a,            dim3(256,2),   dim3(256), 0, stream, qwh, qwl, kf, mask, attn, m_ws, l_ws);
  hipLaunchKernelGGL(k2b,            dim3(512),     dim3(512), 0, stream, vt, m_ws, l_ws, attn, outp);
}

// Round 6
// 349.092 us; speedup vs baseline: 1.3910x; 1.0149x over previous
//
#include <hip/hip_runtime.h>
#include <stdint.h>

#define TQs 2048
#define TKs 2048
#define DDs 512
#define NBs 8

typedef float f32x4 __attribute__((ext_vector_type(4)));
typedef float f32x2 __attribute__((ext_vector_type(2)));
typedef short bf16x8 __attribute__((ext_vector_type(8)));
typedef short bf16x4 __attribute__((ext_vector_type(4)));
typedef short bf16x2 __attribute__((ext_vector_type(2)));
typedef _Float16 half8 __attribute__((ext_vector_type(8)));

__device__ __forceinline__ unsigned short f2bf(float x){
  unsigned u = __float_as_uint(x);
  return (unsigned short)((u + 0x7fffu + ((u>>16)&1u)) >> 16);
}
__device__ __forceinline__ float bf2f(unsigned short h){
  return __uint_as_float(((unsigned)h)<<16);
}

// global -> LDS direct DMA, 16B per lane; LDS dest = uniform base + lane*16.
__device__ __forceinline__ void gload16(const void* g, void* l){
  __builtin_amdgcn_global_load_lds(
      (const __attribute__((address_space(1))) unsigned int*)(unsigned long long)(uintptr_t)g,
      (__attribute__((address_space(3))) unsigned int*)(unsigned int)(uintptr_t)l,
      16, 0, 0);
}

// K0a: k (f32) -> kf (f16)
__global__ __launch_bounds__(256) void k0_kf(const float* __restrict__ kk, _Float16* __restrict__ kf){
  const long n8 = (long)NBs*TKs*DDs/8;
  for(long i = (long)blockIdx.x*256 + threadIdx.x; i < n8; i += (long)gridDim.x*256){
    f32x4 x0 = ((const f32x4*)kk)[2*i];
    f32x4 x1 = ((const f32x4*)kk)[2*i+1];
    half8 h;
    #pragma unroll
    for(int j=0;j<4;j++){ h[j] = (_Float16)x0[j]; h[4+j] = (_Float16)x1[j]; }
    ((half8*)kf)[i] = h;
  }
}

// K0b: v (b,t,d) f32 -> vt (b,d,t) bf16
__global__ __launch_bounds__(256) void k0_transpose_v(const float* __restrict__ v, short* __restrict__ vt){
  __shared__ float tile[64][65];
  int b = blockIdx.z;
  int t0 = blockIdx.x*64, d0 = blockIdx.y*64;
  int tid = threadIdx.x;
  int r = tid>>2, cs = (tid&3)*16;
  const float* src = v + ((long)b*TKs + t0 + r)*DDs + d0 + cs;
  #pragma unroll
  for(int i=0;i<4;i++){
    f32x4 x = ((const f32x4*)src)[i];
    tile[r][cs+4*i+0]=x[0]; tile[r][cs+4*i+1]=x[1]; tile[r][cs+4*i+2]=x[2]; tile[r][cs+4*i+3]=x[3];
  }
  __syncthreads();
  int dr = tid>>2, ts = (tid&3)*16;
  bf16x8 b0, b1;
  #pragma unroll
  for(int i=0;i<8;i++){ b0[i] = (short)f2bf(tile[ts+i][dr]); b1[i] = (short)f2bf(tile[ts+8+i][dr]); }
  short* dst = vt + ((long)b*DDs + d0 + dr)*TKs + t0 + ts;
  ((bf16x8*)dst)[0] = b0;
  ((bf16x8*)dst)[1] = b1;
}

// K0c: w (d,e) f32 -> wth/wtl (e,d) bf16 split
__global__ __launch_bounds__(256) void k0_wt(const float* __restrict__ wsrc,
                                             short* __restrict__ wth, short* __restrict__ wtl){
  __shared__ float tile[64][65];
  int d0 = blockIdx.x*64, e0 = blockIdx.y*64;
  int tid = threadIdx.x;
  int r = tid>>2, cs = (tid&3)*16;
  const float* src = wsrc + ((long)(d0 + r))*DDs + e0 + cs;
  #pragma unroll
  for(int i=0;i<4;i++){
    f32x4 x = ((const f32x4*)src)[i];
    tile[r][cs+4*i+0]=x[0]; tile[r][cs+4*i+1]=x[1]; tile[r][cs+4*i+2]=x[2]; tile[r][cs+4*i+3]=x[3];
  }
  __syncthreads();
  int er = tid>>2, ds = (tid&3)*16;
  bf16x8 h0,h1,l0,l1;
  #pragma unroll
  for(int i=0;i<8;i++){
    float x = tile[ds+i][er];
    unsigned short hh = f2bf(x);
    h0[i] = (short)hh; l0[i] = (short)f2bf(x - bf2f(hh));
  }
  #pragma unroll
  for(int i=0;i<8;i++){
    float x = tile[ds+8+i][er];
    unsigned short hh = f2bf(x);
    h1[i] = (short)hh; l1[i] = (short)f2bf(x - bf2f(hh));
  }
  short* dh = wth + ((long)(e0+er))*DDs + d0 + ds;
  short* dl = wtl + ((long)(e0+er))*DDs + d0 + ds;
  ((bf16x8*)dh)[0] = h0; ((bf16x8*)dh)[1] = h1;
  ((bf16x8*)dl)[0] = l0; ((bf16x8*)dl)[1] = l1;
}

// K1: qw = q @ W (bf16 3-term). Output: f16 hi/lo split.
__global__ __launch_bounds__(256,2) void k1_qw(const float* __restrict__ q,
                                               const short* __restrict__ wth, const short* __restrict__ wtl,
                                               _Float16* __restrict__ qwh, _Float16* __restrict__ qwl){
  __shared__ short qah[8192], qal[8192];
  __shared__ short wbh[8192], wbl[8192];
  int q0 = blockIdx.x*128, e0 = blockIdx.y*128;
  int tid = threadIdx.x, lane = tid&63, w4 = tid>>6;
  int wm = w4>>1, wn = w4&1;
  int i15 = lane&15, g4 = lane>>4;
  f32x4 acc[4][4];
  #pragma unroll
  for(int a=0;a<4;a++)
    #pragma unroll
    for(int bq=0;bq<4;bq++) acc[a][bq] = (f32x4){0.f,0.f,0.f,0.f};
  for(int k0=0;k0<DDs;k0+=64){
    __syncthreads();
    #pragma unroll
    for(int j=0;j<4;j++){
      int J = j*4 + w4;
      long so = (long)(e0 + (J>>1)*16 + i15)*DDs + k0 + ((J&1)*4 + g4)*8;
      gload16(wth + so, &wbh[J*512]);
      gload16(wtl + so, &wbl[J*512]);
    }
    #pragma unroll
    for(int j=0;j<4;j++){
      int c = j*256 + tid;
      int ci = c&15, cg = (c>>4)&3, cks = (c>>6)&1, crb = c>>7;
      const float* s = q + (long)(q0 + crb*16 + ci)*DDs + k0 + (cks*4+cg)*8;
      f32x4 x0 = ((const f32x4*)s)[0];
      f32x4 x1 = ((const f32x4*)s)[1];
      bf16x8 h, l;
      #pragma unroll
      for(int jj=0;jj<4;jj++){
        unsigned short hj = f2bf(x0[jj]);
        h[jj] = (short)hj; l[jj] = (short)f2bf(x0[jj]-bf2f(hj));
      }
      #pragma unroll
      for(int jj=0;jj<4;jj++){
        unsigned short hj = f2bf(x1[jj]);
        h[4+jj] = (short)hj; l[4+jj] = (short)f2bf(x1[jj]-bf2f(hj));
      }
      *(bf16x8*)&qah[c*8] = h;
      *(bf16x8*)&qal[c*8] = l;
    }
    __syncthreads();
    #pragma unroll
    for(int ks=0;ks<2;ks++){
      bf16x8 a_h[4], a_l[4], b_h[4], b_l[4];
      #pragma unroll
      for(int mf=0;mf<4;mf++){
        int c = ((wm*4+mf)*2+ks)*64 + lane;
        a_h[mf] = *(const bf16x8*)&qah[c*8];
        a_l[mf] = *(const bf16x8*)&qal[c*8];
      }
      #pragma unroll
      for(int nf=0;nf<4;nf++){
        int c = ((wn*4+nf)*2+ks)*64 + lane;
        b_h[nf] = *(const bf16x8*)&wbh[c*8];
        b_l[nf] = *(const bf16x8*)&wbl[c*8];
      }
      #pragma unroll
      for(int mf=0;mf<4;mf++)
      #pragma unroll
      for(int nf=0;nf<4;nf++){
        acc[mf][nf] = __builtin_amdgcn_mfma_f32_16x16x32_bf16(a_h[mf], b_h[nf], acc[mf][nf],0,0,0);
        acc[mf][nf] = __builtin_amdgcn_mfma_f32_16x16x32_bf16(a_h[mf], b_l[nf], acc[mf][nf],0,0,0);
        acc[mf][nf] = __builtin_amdgcn_mfma_f32_16x16x32_bf16(a_l[mf], b_h[nf], acc[mf][nf],0,0,0);
      }
    }
  }
  int rr = g4*4, cc = i15;
  #pragma unroll
  for(int mf=0;mf<4;mf++)
  #pragma unroll
  for(int nf=0;nf<4;nf++)
  #pragma unroll
  for(int r2=0;r2<4;r2++){
    long row = q0 + wm*64 + mf*16 + rr + r2;
    long col = e0 + wn*64 + nf*16 + cc;
    float s = acc[mf][nf][r2];
    _Float16 h = (_Float16)s;
    qwh[row*DDs + col] = h;
    qwl[row*DDs + col] = (_Float16)(s - (float)h);
  }
}

// K2a: scores = qw @ k^T, f16 2-term. 32-t K-tiles double-buffered,
// mask prefetched 1 tile ahead; per-lane online (m,l); raw masked S -> attn region.
__global__ __launch_bounds__(256,2) void k2a(const _Float16* __restrict__ qwh, const _Float16* __restrict__ qwl,
                                             const _Float16* __restrict__ kf,
                                             const int* __restrict__ mask, float* __restrict__ attn,
                                             float* __restrict__ m_ws, float* __restrict__ l_ws){
  __shared__ _Float16 kb[2][16384];   // 2 x 32KB
  int rb = blockIdx.x;                // 0..255
  int chunk = blockIdx.y;             // 0..1
  int tid = threadIdx.x, lane = tid&63, w = tid>>6;
  int b = rb>>5;
  long qrow0 = (long)rb*64 + w*16;
  int i15 = lane&15, g4 = lane>>4;
  half8 ah[16], al[16];
  {
    const _Float16* ph = qwh + (qrow0 + i15)*DDs + g4*8;
    const _Float16* pl = qwl + (qrow0 + i15)*DDs + g4*8;
    #pragma unroll
    for(int kc=0;kc<16;kc++){
      ah[kc] = *(const half8*)(ph + kc*32);
      al[kc] = *(const half8*)(pl + kc*32);
    }
  }
  float m_st[4], l_st[4];
  #pragma unroll
  for(int r=0;r<4;r++){ m_st[r]=-1e30f; l_st[r]=0.f; }
  const _Float16* kbase = kf + (long)b*TKs*DDs;
  int mv_pf[2][4];
  // prologue: stage tile 0, prefetch mask tile 0
  {
    int t0 = chunk*1024;
    #pragma unroll
    for(int j=0;j<8;j++){
      int J = j*4 + w;
      long so = (long)(t0 + ((J>>4)<<4) + i15)*DDs + (J&15)*32 + g4*8;
      gload16(kbase + so, &kb[0][J*512]);
    }
    #pragma unroll
    for(int nf=0;nf<2;nf++)
      #pragma unroll
      for(int r=0;r<4;r++)
        mv_pf[nf][r] = mask[(qrow0 + g4*4 + r)*TKs + t0 + nf*16 + i15];
  }
  __syncthreads();
  int cur = 0;
  for(int it=0; it<32; ++it){
    int t0 = chunk*1024 + it*32;
    if(it < 31){
      int t1 = t0 + 32;
      #pragma unroll
      for(int j=0;j<8;j++){
        int J = j*4 + w;
        long so = (long)(t1 + ((J>>4)<<4) + i15)*DDs + (J&15)*32 + g4*8;
        gload16(kbase + so, &kb[cur^1][J*512]);
      }
    }
    int mv[2][4];
    #pragma unroll
    for(int nf=0;nf<2;nf++)
      #pragma unroll
      for(int r=0;r<4;r++)
        mv[nf][r] = mv_pf[nf][r];
    if(it < 31){
      int t1 = t0 + 32;
      #pragma unroll
      for(int nf=0;nf<2;nf++)
        #pragma unroll
        for(int r=0;r<4;r++)
          mv_pf[nf][r] = mask[(qrow0 + g4*4 + r)*TKs + t1 + nf*16 + i15];
    }
    f32x4 acc[2];
    acc[0]=(f32x4){0.f,0.f,0.f,0.f}; acc[1]=(f32x4){0.f,0.f,0.f,0.f};
    #pragma unroll
    for(int ks=0;ks<16;ks++){
      #pragma unroll
      for(int nf=0;nf<2;nf++){
        half8 bh = *(const half8*)&kb[cur][((nf*16+ks)*64 + lane)*8];
        acc[nf] = __builtin_amdgcn_mfma_f32_16x16x32_f16(ah[ks], bh, acc[nf],0,0,0);
        acc[nf] = __builtin_amdgcn_mfma_f32_16x16x32_f16(al[ks], bh, acc[nf],0,0,0);
      }
    }
    #pragma unroll
    for(int r=0;r<4;r++){
      float s0 = acc[0][r];
      float s1 = acc[1][r];
      if(mv[0][r]) s0 = -3e38f;
      if(mv[1][r]) s1 = -3e38f;
      float mo = m_st[r];
      float mn = fmaxf(mo, fmaxf(s0,s1));
      l_st[r] = l_st[r]*__expf(mo-mn) + __expf(s0-mn) + __expf(s1-mn);
      m_st[r] = mn;
      long row = qrow0 + g4*4 + r;
      attn[row*TKs + t0 + i15] = s0;
      attn[row*TKs + t0 + 16 + i15] = s1;
    }
    __syncthreads();
    cur ^= 1;
  }
  // one-time 16-lane merge of (m,l)
  #pragma unroll
  for(int r=0;r<4;r++){
    #pragma unroll
    for(int d=1; d<16; d<<=1){
      float m2 = __shfl_xor(m_st[r], d, 16);
      float l2 = __shfl_xor(l_st[r], d, 16);
      float mn = fmaxf(m_st[r], m2);
      l_st[r] = l_st[r]*__expf(m_st[r]-mn) + l2*__expf(m2-mn);
      m_st[r] = mn;
    }
  }
  if(i15==0){
    #pragma unroll
    for(int r=0;r<4;r++){
      long row = qrow0 + g4*4 + r;
      m_ws[row*2 + chunk] = m_st[r];
      l_ws[row*2 + chunk] = l_st[r];
    }
  }
}

// K2b: merge stats, normalize S -> attention (in place), PV via bf16 MFMA.
// 512 threads (8 waves x 64 dv), 32 rows/block. S prefetched DEPTH-2 into regs;
// V DMA double-buffered; at2 writes wave-contiguous (bank-conflict-free).
__global__ __launch_bounds__(512,4) void k2b(const short* __restrict__ vt, const float* __restrict__ m_ws,
                                             const float* __restrict__ l_ws, float* __restrict__ attn,
                                             float* __restrict__ outp){
  __shared__ short vf[2][16384];   // 2 x 32KB: 32 cells of 16dv x 32t
  __shared__ short at2[2][1024];   // 2 x 2KB
  __shared__ float ms[32], rls[32];
  int rb = blockIdx.x;             // 0..511
  long row0 = (long)rb*32;
  int b = rb>>6;
  int tid=threadIdx.x, lane=tid&63, w=tid>>6;
  int i15 = lane&15, g4 = lane>>4;
  const short* vb = vt + (long)b*DDs*TKs;
  float* arow = attn + row0*TKs;
  // normalize mapping: row r_n, even t-offset tn; at2 byte = w*256 + lane*4 (conflict-free)
  int r_n = ((tid>>8)<<4) | (lane>>2);
  int tn  = (((tid>>6)&3)<<3) | ((lane&3)<<1);
  int nbyte = ((tid>>6)<<8) | (lane<<2);
  // prologue: DMA v tile 0; prefetch S tile 0; stats
  #pragma unroll
  for(int j=0;j<4;j++){
    int J = j*8 + w;
    long so = (long)(J*16 + i15)*TKs + g4*8;
    gload16(vb + so, &vf[0][J*512]);
  }
  f32x2 s_pf = *(const f32x2*)(arow + (long)r_n*TKs + tn);
  if(tid < 32){
    long row = row0 + tid;
    float m0=m_ws[row*2+0], m1=m_ws[row*2+1];
    float M = fmaxf(m0,m1);
    float L = l_ws[row*2+0]*__expf(m0-M) + l_ws[row*2+1]*__expf(m1-M);
    ms[tid] = M;
    rls[tid] = 1.0f/L;
  }
  __syncthreads();   // ms/rls ready; V0 DMA complete
  // normalize tile 0 -> at2[0] + attn
  {
    float M = ms[r_n], RL = rls[r_n];
    float a0 = __expf(s_pf[0]-M)*RL, a1 = __expf(s_pf[1]-M)*RL;
    f32x2 av; av[0]=a0; av[1]=a1;
    *(f32x2*)(arow + (long)r_n*TKs + tn) = av;
    bf16x2 ab; ab[0]=(short)f2bf(a0); ab[1]=(short)f2bf(a1);
    *(bf16x2*)((char*)at2[0] + nbyte) = ab;
  }
  s_pf = *(const f32x2*)(arow + (long)r_n*TKs + 32 + tn);   // S tile 1
  __syncthreads();   // at2[0] visible
  f32x4 acc[2][4];
  #pragma unroll
  for(int mf=0;mf<2;mf++)
    #pragma unroll
    for(int nf=0;nf<4;nf++) acc[mf][nf]=(f32x4){0.f,0.f,0.f,0.f};
  int c = 0;
  for(int it=0; it<64; ++it){
    if(it < 63){
      int t1 = (it+1)*32;
      #pragma unroll
      for(int j=0;j<4;j++){
        int J = j*8 + w;
        long so = (long)(J*16 + i15)*TKs + t1 + g4*8;
        gload16(vb + so, &vf[c^1][J*512]);
      }
    }
    f32x2 s_cur = s_pf;
    if(it < 62)
      s_pf = *(const f32x2*)(arow + (long)r_n*TKs + (it+2)*32 + tn);
    // MFMA on current tile
    bf16x8 af[2], bfr[4];
    #pragma unroll
    for(int mf=0;mf<2;mf++) af[mf] = *(const bf16x8*)&at2[c][(mf*64 + lane)*8];
    #pragma unroll
    for(int nf=0;nf<4;nf++) bfr[nf] = *(const bf16x8*)&vf[c][((w*4+nf)*64 + lane)*8];
    #pragma unroll
    for(int mf=0;mf<2;mf++)
    #pragma unroll
    for(int nf=0;nf<4;nf++)
      acc[mf][nf] = __builtin_amdgcn_mfma_f32_16x16x32_bf16(af[mf], bfr[nf], acc[mf][nf],0,0,0);
    // normalize tile it+1 from registers into at2[c^1] + attn
    if(it < 63){
      int t1 = (it+1)*32;
      float M = ms[r_n], RL = rls[r_n];
      float a0 = __expf(s_cur[0]-M)*RL, a1 = __expf(s_cur[1]-M)*RL;
      f32x2 av; av[0]=a0; av[1]=a1;
      *(f32x2*)(arow + (long)r_n*TKs + t1 + tn) = av;
      bf16x2 ab; ab[0]=(short)f2bf(a0); ab[1]=(short)f2bf(a1);
      *(bf16x2*)((char*)at2[c^1] + nbyte) = ab;
    }
    __syncthreads();
    c ^= 1;
  }
  #pragma unroll
  for(int mf=0;mf<2;mf++)
  #pragma unroll
  for(int nf=0;nf<4;nf++)
  #pragma unroll
  for(int r2=0;r2<4;r2++){
    long row = row0 + mf*16 + g4*4 + r2;
    long col = w*64 + nf*16 + i15;
    outp[row*DDs + col] = acc[mf][nf][r2];
  }
}

extern "C" void kernel_launch(void* const* d_in, const int* in_sizes, int n_in,
                              void* d_out, int out_size, void* d_ws, size_t ws_size,
                              hipStream_t stream) {
  const float* q    = (const float*)d_in[0];
  const float* k    = (const float*)d_in[1];
  const float* v    = (const float*)d_in[2];
  const int*   mask = (const int*)d_in[3];
  const float* wsrc = (const float*)d_in[4];
  float* outp = (float*)d_out;
  float* attn = (float*)d_out + (long)NBs*TQs*DDs;
  char* ws = (char*)d_ws;
  const long NE = (long)NBs*TKs*DDs;      // 8,388,608 elements
  _Float16* kf  = (_Float16*)ws;                 // 2NE bytes
  short*    vt  = (short*)(ws + 2*NE);           // 2NE bytes
  _Float16* qwh = (_Float16*)(ws + 4*NE);        // 2NE bytes
  _Float16* qwl = (_Float16*)(ws + 6*NE);        // 2NE bytes
  float* m_ws = (float*)(ws + 8*NE);             // 32768 f32 used
  float* l_ws = (float*)(ws + 8*NE + 65536*4);
  // wt split lives at the head of the attn region (dead before k2a overwrites it)
  short* wth = (short*)attn;
  short* wtl = (short*)attn + 262144;
  hipLaunchKernelGGL(k0_kf,          dim3(1024),    dim3(256), 0, stream, k, kf);
  hipLaunchKernelGGL(k0_transpose_v, dim3(32,8,8),  dim3(256), 0, stream, v, vt);
  hipLaunchKernelGGL(k0_wt,          dim3(8,8),     dim3(256), 0, stream, wsrc, wth, wtl);
  hipLaunchKernelGGL(k1_qw,          dim3(128,4),   dim3(256), 0, stream, q, wth, wtl, qwh, qwl);
  hipLaunchKernelGGL(k2a,            dim3(256,2),   dim3(256), 0, stream, qwh, qwl, kf, mask, attn, m_ws, l_ws);
  hipLaunchKernelGGL(k2b,            dim3(512),     dim3(512), 0, stream, vt, m_ws, l_ws, attn, outp);
}